// Round 1
// 166.830 us; speedup vs baseline: 1.0358x; 1.0358x over previous
//
#include <hip/hip_runtime.h>
#include <math.h>

#define M_SPATIAL 2097152  // 128^3
#define MV4 (M_SPATIAL / 4)

__device__ __forceinline__ float wave_redf(float v) {
#pragma unroll
  for (int o = 32; o > 0; o >>= 1) v += __shfl_down(v, o, 64);
  return v;
}
__device__ __forceinline__ double wave_redd(double v) {
#pragma unroll
  for (int o = 32; o > 0; o >>= 1) v += __shfl_down(v, o, 64);
  return v;
}

// part layout (doubles):
// [0..1023]=ce  [1024..2047]=p  [2048..3071]=pt  [3072..4095]=t  [4096..5119]=dist
// kA blocks 0..511 -> b=0, 512..1023 -> b=1 (same for kD's blk>>9).

// ---------------------------------------------------------------------------
// kA: streaming CE + dice partials (float4/int4, per-block slots, no atomics).
// ---------------------------------------------------------------------------
__global__ __launch_bounds__(256) void kA_ce(const float4* __restrict__ outputs4,
                                             const int4* __restrict__ y4,
                                             double* __restrict__ part) {
  int blk = blockIdx.x;                 // 0..1023
  int base = blk * 1024;                // vec4 slots
  int b = (blk >= 512) ? 1 : 0;
  const float4* xc = outputs4 + (size_t)(b * 2 + 1) * MV4;
  float ce = 0.f, ps = 0.f, pts = 0.f, tsum = 0.f;
#pragma unroll
  for (int k = 0; k < 4; ++k) {
    int v4 = base + (int)threadIdx.x + k * 256;
    int s4 = v4 & (MV4 - 1);
    int4 yv = y4[v4];
    float4 x = xc[s4];
#define ELEM(c, yc)                                                         \
    {                                                                       \
      float t = (yc == 1) ? 1.0f : 0.0f;                                    \
      float xx = x.c;                                                       \
      ce += fmaxf(xx, 0.0f) - xx * t + log1pf(expf(-fabsf(xx)));            \
      float p = 1.0f / (1.0f + expf(-xx));                                  \
      ps += p; pts += p * t; tsum += t;                                     \
    }
    ELEM(x, yv.x) ELEM(y, yv.y) ELEM(z, yv.z) ELEM(w, yv.w)
#undef ELEM
  }
  float r0 = wave_redf(ce), r1 = wave_redf(ps), r2 = wave_redf(pts), r3 = wave_redf(tsum);
  __shared__ float sm[4][4];
  int lane = threadIdx.x & 63, w = threadIdx.x >> 6;
  if (lane == 0) { sm[w][0] = r0; sm[w][1] = r1; sm[w][2] = r2; sm[w][3] = r3; }
  __syncthreads();
  if (threadIdx.x == 0) {
    part[blk]        = (double)(sm[0][0] + sm[1][0] + sm[2][0] + sm[3][0]);
    part[1024 + blk] = (double)(sm[0][1] + sm[1][1] + sm[2][1] + sm[3][1]);
    part[2048 + blk] = (double)(sm[0][2] + sm[1][2] + sm[2][2] + sm[3][2]);
    part[3072 + blk] = (double)(sm[0][3] + sm[1][3] + sm[2][3] + sm[3][3]);
  }
}

// ---------------------------------------------------------------------------
// kB: X-axis EDT via blocked parallel scan. 1024 blocks x 256 threads
// (4 waves/SIMD vs old 0.5). Thread owns a 16-x chunk of one (yy,z) line,
// held entirely in registers (16-deep MLP). Chunk carries (last-bg /
// next-bg absolute positions) exchanged via 2 KB LDS; exact integer
// semantics identical to the old serial two-scan (saturate 200, >=128 -> inf).
// Writes h = gX + y^2 for the Y pass.
// ---------------------------------------------------------------------------
__global__ __launch_bounds__(256) void kB_edtx(const int* __restrict__ y,
                                               float* __restrict__ g) {
  int blk = blockIdx.x;            // b*512 + yy*4 + zq
  int b  = blk >> 9;
  int yy = (blk >> 2) & 127;
  int zq = blk & 3;
  int t  = threadIdx.x;
  int c  = t >> 5;                 // x-chunk 0..7 (16 x each)
  int zl = t & 31;                 // z within 32-chunk
  int x0 = c * 16;
  size_t base = (size_t)b * M_SPATIAL + (size_t)yy * 128 + (size_t)zq * 32 + zl;

  int yb[16];
#pragma unroll
  for (int k = 0; k < 16; ++k) yb[k] = y[base + (size_t)(x0 + k) * 16384];

  // Local chunk summaries: last bg position (or -200), first bg position (or 400).
  int lastE = -200, nextE = 400;
#pragma unroll
  for (int k = 0; k < 16; ++k) lastE = (yb[k] == 1) ? lastE : (x0 + k);
#pragma unroll
  for (int k = 15; k >= 0; --k) nextE = (yb[k] == 1) ? nextE : (x0 + k);

  __shared__ int lE[8][32];
  __shared__ int nE[8][32];
  lE[c][zl] = lastE;
  nE[c][zl] = nextE;
  __syncthreads();

  int carryL = -200, carryN = 400;
#pragma unroll
  for (int q = 0; q < 7; ++q) {
    if (q < c)     carryL = max(carryL, lE[q][zl]);       // chunks before c
    if (q + 1 > c) carryN = min(carryN, nE[q + 1][zl]);   // chunks after c
  }

  float yy2f = (float)(yy * yy);
  float hinf = 1000000.f + yy2f;

  // Forward rescan with carry: d_fwd = min(x - lastbg, 200).
  int df[16];
  int ll = carryL;
#pragma unroll
  for (int k = 0; k < 16; ++k) {
    ll = (yb[k] == 1) ? ll : (x0 + k);
    df[k] = min(x0 + k - ll, 200);
  }
  // Backward rescan + output: m = min(d_fwd, d_bwd); m>=128 means no bg in line.
  float ov[16];
  int nn = carryN;
#pragma unroll
  for (int k = 15; k >= 0; --k) {
    nn = (yb[k] == 1) ? nn : (x0 + k);
    int m = min(df[k], min(nn - (x0 + k), 200));
    ov[k] = (m >= 128) ? hinf : ((float)(m * m) + yy2f);
  }
#pragma unroll
  for (int k = 0; k < 16; ++k) g[base + (size_t)(x0 + k) * 16384] = ov[k];
}

// ---------------------------------------------------------------------------
// kC: Y-axis pass. Inner loop now processes parabolas in pairs so the
// reduction folds to v_min3_f32: 2 fma + 1 min3 per 2 j (was 2 instr/j).
// In-place on g. Writes h' = dY + z^2 for the Z pass.
// ---------------------------------------------------------------------------
__global__ __launch_bounds__(256) void kC_edty(float* __restrict__ g) {
  __shared__ float hl[128 * 33];   // hl[j*33 + zl]
  int blk = blockIdx.x;            // b*512 + xx*4 + zc
  int b = blk >> 9, xx = (blk >> 2) & 127, zc = blk & 3;
  int t = threadIdx.x;
  size_t rb = (size_t)b * M_SPATIAL + (size_t)xx * 16384 + (size_t)zc * 32;

#pragma unroll
  for (int r = 0; r < 4; ++r) {
    int i4 = t + r * 256;          // 0..1023 float4 units
    int j = i4 >> 3, w = i4 & 7;   // row j, 4*w z-offset
    float4 v = *(const float4*)(g + rb + (size_t)j * 128 + 4 * w);
    hl[j * 33 + 4 * w + 0] = v.x;
    hl[j * 33 + 4 * w + 1] = v.y;
    hl[j * 33 + 4 * w + 2] = v.z;
    hl[j * 33 + 4 * w + 3] = v.w;
  }
  __syncthreads();

  int zl = t & 31, ig = t >> 5;
  float best[16], mc[16];
#pragma unroll
  for (int k = 0; k < 16; ++k) {
    best[k] = 3.0e38f;
    mc[k] = -2.0f * (float)(ig * 16 + k);
  }
#pragma unroll 2
  for (int j = 0; j < 128; j += 2) {
    float h0 = hl[j * 33 + zl];
    float h1 = hl[(j + 1) * 33 + zl];
    float j0 = (float)j, j1 = (float)(j + 1);
#pragma unroll
    for (int k = 0; k < 16; ++k)
      best[k] = fminf(fminf(fmaf(mc[k], j0, h0), fmaf(mc[k], j1, h1)), best[k]);
  }
  int gz = zc * 32 + zl;
  float zq = (float)(gz * gz);
  size_t ob = rb + zl;
#pragma unroll
  for (int k = 0; k < 16; ++k) {
    int i = ig * 16 + k;
    float dY = (float)(i * i) + best[k];   // exact int
    g[ob + (size_t)i * 128] = dY + zq;     // h for Z pass
  }
}

// ---------------------------------------------------------------------------
// kD: Z-axis pass (contiguous lines) + fused dist-loss partial.
// Same min3 pairing as kC.
// ---------------------------------------------------------------------------
__global__ __launch_bounds__(256) void kD_edtz_dist(const float* __restrict__ g,
                                                    const float* __restrict__ od,
                                                    double* __restrict__ part) {
  __shared__ float hl[128 * 33];   // hl[z*33 + yl]
  __shared__ float sred[4];
  int blk = blockIdx.x;            // b*512 + xx*4 + yc
  int b = blk >> 9, xx = (blk >> 2) & 127, yc = blk & 3;
  int t = threadIdx.x;
  size_t rb = (size_t)b * M_SPATIAL + (size_t)xx * 16384 + (size_t)yc * 4096;
  int yl = t & 31, ig = t >> 5;

  // Prefetch od (this thread's 16 consecutive z) early to hide latency.
  size_t odb = (size_t)(2 * b + 1) * M_SPATIAL + (size_t)xx * 16384 +
               (size_t)yc * 4096 + (size_t)yl * 128 + (size_t)ig * 16;
  const float4* o4 = (const float4*)(od + odb);
  float4 ov[4];
#pragma unroll
  for (int r = 0; r < 4; ++r) ov[r] = o4[r];

  const float4* h4 = (const float4*)(g + rb);
#pragma unroll
  for (int r = 0; r < 4; ++r) {
    int i4 = t + r * 256;
    float4 v = h4[i4];
    int flat = i4 * 4;
    int z = flat & 127, yw = flat >> 7;  // z%4==0, all 4 comps same yw
    hl[(z + 0) * 33 + yw] = v.x;
    hl[(z + 1) * 33 + yw] = v.y;
    hl[(z + 2) * 33 + yw] = v.z;
    hl[(z + 3) * 33 + yw] = v.w;
  }
  __syncthreads();

  float best[16], mc[16];
#pragma unroll
  for (int k = 0; k < 16; ++k) {
    best[k] = 3.0e38f;
    mc[k] = -2.0f * (float)(ig * 16 + k);
  }
#pragma unroll 2
  for (int j = 0; j < 128; j += 2) {
    float h0 = hl[j * 33 + yl];
    float h1 = hl[(j + 1) * 33 + yl];
    float j0 = (float)j, j1 = (float)(j + 1);
#pragma unroll
    for (int k = 0; k < 16; ++k)
      best[k] = fminf(fminf(fmaf(mc[k], j0, h0), fmaf(mc[k], j1, h1)), best[k]);
  }
  const float* of = (const float*)ov;
  float dist = 0.f;
#pragma unroll
  for (int k = 0; k < 16; ++k) {
    int i = ig * 16 + k;
    float dv = (float)(i * i) + best[k];   // exact squared EDT
    if (dv > 0.f) dist += fabsf(of[k] - sqrtf(dv));
  }
  float r = wave_redf(dist);
  int lane = t & 63, w = t >> 6;
  if (lane == 0) sred[w] = r;
  __syncthreads();
  if (t == 0) part[4096 + blk] = (double)(sred[0] + sred[1] + sred[2] + sred[3]);
}

// ---------------------------------------------------------------------------
// k_final: reduce 5x1024 partials, combine to scalar loss.
// ---------------------------------------------------------------------------
__global__ __launch_bounds__(256) void k_final(const double* __restrict__ part,
                                               const float* __restrict__ wptr,
                                               float* __restrict__ out) {
  int i = threadIdx.x;
  double ce  = part[i] + part[i + 256] + part[i + 512] + part[i + 768];
  double p0  = part[1024 + i] + part[1024 + i + 256];
  double p1  = part[1536 + i] + part[1536 + i + 256];
  double pt0 = part[2048 + i] + part[2048 + i + 256];
  double pt1 = part[2560 + i] + part[2560 + i + 256];
  double t0  = part[3072 + i] + part[3072 + i + 256];
  double t1  = part[3584 + i] + part[3584 + i + 256];
  double ds  = part[4096 + i] + part[4096 + i + 256] + part[4096 + i + 512] + part[4096 + i + 768];

  ce = wave_redd(ce); p0 = wave_redd(p0); p1 = wave_redd(p1);
  pt0 = wave_redd(pt0); pt1 = wave_redd(pt1);
  t0 = wave_redd(t0); t1 = wave_redd(t1); ds = wave_redd(ds);

  __shared__ double sm[4][8];
  int lane = threadIdx.x & 63, w = threadIdx.x >> 6;
  if (lane == 0) {
    sm[w][0] = ce; sm[w][1] = p0; sm[w][2] = p1; sm[w][3] = pt0;
    sm[w][4] = pt1; sm[w][5] = t0; sm[w][6] = t1; sm[w][7] = ds;
  }
  __syncthreads();
  if (threadIdx.x == 0) {
    double a[8];
    for (int q = 0; q < 8; ++q) a[q] = sm[0][q] + sm[1][q] + sm[2][q] + sm[3][q];
    double cem = a[0] / 4194304.0;
    double dice0 = (2.0 * a[3] + 1.0) / (a[1] + a[5] + 1.0);
    double dice1 = (2.0 * a[4] + 1.0) / (a[2] + a[6] + 1.0);
    double ldice = 1.0 - 0.5 * (dice0 + dice1);
    double msum = a[5] + a[6];
    double ldist = (msum == 0.0) ? 0.0 : a[7] / fmax(msum, 1e-12);
    out[0] = (float)(cem + ldice + (double)wptr[0] * ldist);
  }
}

extern "C" void kernel_launch(void* const* d_in, const int* in_sizes, int n_in,
                              void* d_out, int out_size, void* d_ws, size_t ws_size,
                              hipStream_t stream) {
  const float* outputs      = (const float*)d_in[0];
  const float* outputs_dist = (const float*)d_in[1];
  const int*   y            = (const int*)d_in[2];
  const float* wptr         = (const float*)d_in[3];
  float* out = (float*)d_out;

  double* part = (double*)d_ws;                    // 5120 doubles = 40 KiB
  float* g = (float*)((char*)d_ws + 65536);        // 16 MiB h/g field

  kA_ce<<<1024, 256, 0, stream>>>((const float4*)outputs, (const int4*)y, part);
  kB_edtx<<<1024, 256, 0, stream>>>(y, g);         // X scan -> h = gX + y^2
  kC_edty<<<1024, 256, 0, stream>>>(g);            // Y pass -> h = dY + z^2
  kD_edtz_dist<<<1024, 256, 0, stream>>>(g, outputs_dist, part);  // Z + dist
  k_final<<<1, 256, 0, stream>>>(part, wptr, out);
}

// Round 3
// 160.152 us; speedup vs baseline: 1.0790x; 1.0417x over previous
//
#include <hip/hip_runtime.h>
#include <math.h>

#define M_SPATIAL 2097152  // 128^3

__device__ __forceinline__ float wave_redf(float v) {
#pragma unroll
  for (int o = 32; o > 0; o >>= 1) v += __shfl_down(v, o, 64);
  return v;
}
__device__ __forceinline__ double wave_redd(double v) {
#pragma unroll
  for (int o = 32; o > 0; o >>= 1) v += __shfl_down(v, o, 64);
  return v;
}

// part layout (doubles):
// [0..1023]=ce  [1024..2047]=p  [2048..3071]=pt  [3072..4095]=t
// [4096..4351]=dist (256 kCD blocks)

// ---------------------------------------------------------------------------
// kAB: X-axis EDT (blocked parallel scan) FUSED with CE + dice partials.
// Thread owns a 16-x chunk of one (yy,z) line; the same y[] elements feed
// both the EDT scan and the CE/dice sums (y is read exactly once).
// NOTE: xc is already batch-offset -> index with SPATIAL-ONLY sp, not base
// (round-2 crash: base includes b*M_SPATIAL, double-counting the batch -> OOB).
// Writes h = gX + y^2 for the Y pass.
// ---------------------------------------------------------------------------
__global__ __launch_bounds__(256) void kAB(const int* __restrict__ y,
                                           const float* __restrict__ outputs,
                                           float* __restrict__ g,
                                           double* __restrict__ part) {
  int blk = blockIdx.x;            // b*512 + yy*4 + zq
  int b  = blk >> 9;
  int yy = (blk >> 2) & 127;
  int zq = blk & 3;
  int t  = threadIdx.x;
  int c  = t >> 5;                 // x-chunk 0..7 (16 x each)
  int zl = t & 31;                 // z within 32-chunk
  int x0 = c * 16;
  size_t sp   = (size_t)yy * 128 + (size_t)zq * 32 + zl;    // spatial-only
  size_t base = (size_t)b * M_SPATIAL + sp;                 // batch + spatial
  const float* xc = outputs + (size_t)(b * 2 + 1) * M_SPATIAL;

  int yb[16];
  float xv[16];
#pragma unroll
  for (int k = 0; k < 16; ++k) yb[k] = y[base + (size_t)(x0 + k) * 16384];
#pragma unroll
  for (int k = 0; k < 16; ++k) xv[k] = xc[sp + (size_t)(x0 + k) * 16384];

  // Local chunk summaries: last bg position (or -200), first bg position (or 400).
  int lastE = -200, nextE = 400;
#pragma unroll
  for (int k = 0; k < 16; ++k) lastE = (yb[k] == 1) ? lastE : (x0 + k);
#pragma unroll
  for (int k = 15; k >= 0; --k) nextE = (yb[k] == 1) ? nextE : (x0 + k);

  __shared__ int lE[8][32];
  __shared__ int nE[8][32];
  lE[c][zl] = lastE;
  nE[c][zl] = nextE;
  __syncthreads();

  int carryL = -200, carryN = 400;
#pragma unroll
  for (int q = 0; q < 7; ++q) {
    if (q < c)     carryL = max(carryL, lE[q][zl]);       // chunks before c
    if (q + 1 > c) carryN = min(carryN, nE[q + 1][zl]);   // chunks after c
  }

  float yy2f = (float)(yy * yy);
  float hinf = 1000000.f + yy2f;

  // Forward rescan with carry: d_fwd = min(x - lastbg, 200).
  int df[16];
  int ll = carryL;
#pragma unroll
  for (int k = 0; k < 16; ++k) {
    ll = (yb[k] == 1) ? ll : (x0 + k);
    df[k] = min(x0 + k - ll, 200);
  }
  // Backward rescan + output: m = min(d_fwd, d_bwd); m>=128 means no bg in line.
  float ov[16];
  int nn = carryN;
#pragma unroll
  for (int k = 15; k >= 0; --k) {
    nn = (yb[k] == 1) ? nn : (x0 + k);
    int m = min(df[k], min(nn - (x0 + k), 200));
    ov[k] = (m >= 128) ? hinf : ((float)(m * m) + yy2f);
  }
#pragma unroll
  for (int k = 0; k < 16; ++k) g[base + (size_t)(x0 + k) * 16384] = ov[k];

  // CE + dice partials on the same 16 elements.
  float ce = 0.f, ps = 0.f, pts = 0.f, tsum = 0.f;
#pragma unroll
  for (int k = 0; k < 16; ++k) {
    float tt = (yb[k] == 1) ? 1.0f : 0.0f;
    float xx = xv[k];
    ce += fmaxf(xx, 0.0f) - xx * tt + log1pf(expf(-fabsf(xx)));
    float p = 1.0f / (1.0f + expf(-xx));
    ps += p; pts += p * tt; tsum += tt;
  }
  float r0 = wave_redf(ce), r1 = wave_redf(ps), r2 = wave_redf(pts), r3 = wave_redf(tsum);
  __shared__ float sm[4][4];
  int lane = t & 63, w = t >> 6;
  if (lane == 0) { sm[w][0] = r0; sm[w][1] = r1; sm[w][2] = r2; sm[w][3] = r3; }
  __syncthreads();
  if (t == 0) {
    part[blk]        = (double)(sm[0][0] + sm[1][0] + sm[2][0] + sm[3][0]);
    part[1024 + blk] = (double)(sm[0][1] + sm[1][1] + sm[2][1] + sm[3][1]);
    part[2048 + blk] = (double)(sm[0][2] + sm[1][2] + sm[2][2] + sm[3][2]);
    part[3072 + blk] = (double)(sm[0][3] + sm[1][3] + sm[2][3] + sm[3][3]);
  }
}

// ---------------------------------------------------------------------------
// kCD: Y pass + Z pass + dist loss, one block per (b,x) slab (128y x 128z =
// 64 KB, lives entirely in LDS; single buffer reused in-place across passes).
// Eliminates the Y-pass global write and Z-pass global re-read (33.5 MB).
// 512 threads = 8 waves; 1 block/CU (67.6 KB LDS; gfx950 allows 160 KB/wg).
//   stage:  sbuf[y*132 + z]                  (banks (4y+z)%32 -> 2-way max)
//   Y pass: thread (z = t&127, 32 i's), writes sbuf[z*129 + i] = dY + z^2
//                                            (banks (z+i)%32 -> 2-way max)
//   Z pass: thread (y = t>>2, 32 i's), reads sbuf[j*129 + y] (broadcast),
//           od loaded as 8x float4 before the j-loop (latency hidden).
// ---------------------------------------------------------------------------
__global__ __launch_bounds__(512) void kCD(const float* __restrict__ g,
                                           const float* __restrict__ od,
                                           double* __restrict__ part) {
  __shared__ float sbuf[128 * 132];   // 67.6 KB, reused across passes
  __shared__ float sred[8];
  int blk = blockIdx.x;               // b*128 + x
  int b = blk >> 7, xx = blk & 127;
  int t = threadIdx.x;
  size_t rb = (size_t)b * M_SPATIAL + (size_t)xx * 16384;

  // Stage the slab: 4096 float4, coalesced.
  const float4* g4 = (const float4*)(g + rb);
#pragma unroll
  for (int r = 0; r < 8; ++r) {
    int i4 = t + r * 512;             // 0..4095
    float4 v = g4[i4];
    int flat = i4 * 4;
    int ys = flat >> 7, zs = flat & 127;
    *(float4*)&sbuf[ys * 132 + zs] = v;
  }
  __syncthreads();

  // ---- Y pass: z = t&127 fixed, i in [ibase, ibase+32).
  {
    int z = t & 127, ibase = (t >> 7) * 32;
    float zq = (float)(z * z);
    float best[32], mc[32];
#pragma unroll
    for (int k = 0; k < 32; ++k) {
      best[k] = 3.0e38f;
      mc[k] = -2.0f * (float)(ibase + k);
    }
#pragma unroll 2
    for (int j = 0; j < 128; j += 2) {
      float h0 = sbuf[j * 132 + z];
      float h1 = sbuf[(j + 1) * 132 + z];
      float j0 = (float)j, j1 = (float)(j + 1);
#pragma unroll
      for (int k = 0; k < 32; ++k)
        best[k] = fminf(fminf(fmaf(mc[k], j0, h0), fmaf(mc[k], j1, h1)), best[k]);
    }
    __syncthreads();                  // everyone done READING sbuf
#pragma unroll
    for (int k = 0; k < 32; ++k) {
      int i = ibase + k;
      float dY = (float)(i * i) + best[k];   // exact int
      sbuf[z * 129 + i] = dY + zq;           // h for Z pass, transposed layout
    }
  }
  __syncthreads();

  // ---- Z pass + dist loss: y = t>>2 fixed, i(z) in [izb, izb+32).
  int yl = t >> 2, izb = (t & 3) * 32;
  size_t odb = (size_t)(2 * b + 1) * M_SPATIAL + (size_t)xx * 16384 +
               (size_t)yl * 128 + (size_t)izb;
  const float4* o4 = (const float4*)(od + odb);
  float4 ovv[8];
#pragma unroll
  for (int r = 0; r < 8; ++r) ovv[r] = o4[r];   // in flight during j-loop

  float best[32], mc[32];
#pragma unroll
  for (int k = 0; k < 32; ++k) {
    best[k] = 3.0e38f;
    mc[k] = -2.0f * (float)(izb + k);
  }
#pragma unroll 2
  for (int j = 0; j < 128; j += 2) {
    float h0 = sbuf[j * 129 + yl];
    float h1 = sbuf[(j + 1) * 129 + yl];
    float j0 = (float)j, j1 = (float)(j + 1);
#pragma unroll
    for (int k = 0; k < 32; ++k)
      best[k] = fminf(fminf(fmaf(mc[k], j0, h0), fmaf(mc[k], j1, h1)), best[k]);
  }
  const float* of = (const float*)ovv;
  float dist = 0.f;
#pragma unroll
  for (int k = 0; k < 32; ++k) {
    int i = izb + k;
    float dv = (float)(i * i) + best[k];     // exact squared EDT
    if (dv > 0.f) dist += fabsf(of[k] - sqrtf(dv));
  }
  float r = wave_redf(dist);
  int lane = t & 63, w = t >> 6;
  if (lane == 0) sred[w] = r;
  __syncthreads();
  if (t == 0) {
    float s = 0.f;
#pragma unroll
    for (int q = 0; q < 8; ++q) s += sred[q];
    part[4096 + blk] = (double)s;
  }
}

// ---------------------------------------------------------------------------
// k_final: reduce partials (1024 ce/dice slots, 256 dist slots) -> loss.
// ---------------------------------------------------------------------------
__global__ __launch_bounds__(256) void k_final(const double* __restrict__ part,
                                               const float* __restrict__ wptr,
                                               float* __restrict__ out) {
  int i = threadIdx.x;
  double ce  = part[i] + part[i + 256] + part[i + 512] + part[i + 768];
  double p0  = part[1024 + i] + part[1024 + i + 256];
  double p1  = part[1536 + i] + part[1536 + i + 256];
  double pt0 = part[2048 + i] + part[2048 + i + 256];
  double pt1 = part[2560 + i] + part[2560 + i + 256];
  double t0  = part[3072 + i] + part[3072 + i + 256];
  double t1  = part[3584 + i] + part[3584 + i + 256];
  double ds  = part[4096 + i];   // 256 kCD blocks, one slot per thread

  ce = wave_redd(ce); p0 = wave_redd(p0); p1 = wave_redd(p1);
  pt0 = wave_redd(pt0); pt1 = wave_redd(pt1);
  t0 = wave_redd(t0); t1 = wave_redd(t1); ds = wave_redd(ds);

  __shared__ double sm[4][8];
  int lane = threadIdx.x & 63, w = threadIdx.x >> 6;
  if (lane == 0) {
    sm[w][0] = ce; sm[w][1] = p0; sm[w][2] = p1; sm[w][3] = pt0;
    sm[w][4] = pt1; sm[w][5] = t0; sm[w][6] = t1; sm[w][7] = ds;
  }
  __syncthreads();
  if (threadIdx.x == 0) {
    double a[8];
    for (int q = 0; q < 8; ++q) a[q] = sm[0][q] + sm[1][q] + sm[2][q] + sm[3][q];
    double cem = a[0] / 4194304.0;
    double dice0 = (2.0 * a[3] + 1.0) / (a[1] + a[5] + 1.0);
    double dice1 = (2.0 * a[4] + 1.0) / (a[2] + a[6] + 1.0);
    double ldice = 1.0 - 0.5 * (dice0 + dice1);
    double msum = a[5] + a[6];
    double ldist = (msum == 0.0) ? 0.0 : a[7] / fmax(msum, 1e-12);
    out[0] = (float)(cem + ldice + (double)wptr[0] * ldist);
  }
}

extern "C" void kernel_launch(void* const* d_in, const int* in_sizes, int n_in,
                              void* d_out, int out_size, void* d_ws, size_t ws_size,
                              hipStream_t stream) {
  const float* outputs      = (const float*)d_in[0];
  const float* outputs_dist = (const float*)d_in[1];
  const int*   y            = (const int*)d_in[2];
  const float* wptr         = (const float*)d_in[3];
  float* out = (float*)d_out;

  double* part = (double*)d_ws;                    // 4352 doubles
  float* g = (float*)((char*)d_ws + 65536);        // 16 MiB h field

  kAB<<<1024, 256, 0, stream>>>(y, outputs, g, part);      // X scan + CE/dice
  kCD<<<256, 512, 0, stream>>>(g, outputs_dist, part);     // Y+Z EDT + dist
  k_final<<<1, 256, 0, stream>>>(part, wptr, out);
}